// Round 17
// baseline (332.967 us; speedup 1.0000x reference)
//
#include <hip/hip_runtime.h>
#include <hip/hip_bf16.h>

#define DEV __device__ __forceinline__

typedef __attribute__((ext_vector_type(8))) short s8v;     // 8 bf16 (4 VGPR)
typedef __attribute__((ext_vector_type(16))) float f32x16; // MFMA 32x32 acc
typedef __attribute__((address_space(1))) const unsigned int u32g;
typedef __attribute__((address_space(3))) unsigned int u32l;

DEV void gl_lds(const void* g, void* l){   // 16B async global->LDS
  __builtin_amdgcn_global_load_lds((u32g*)g, (u32l*)l, 16, 0, 0);
}

DEV float siluf(float x){ return x / (1.f + expf(-x)); }

DEV float wredsum(float v){
  #pragma unroll
  for(int m = 32; m; m >>= 1) v += __shfl_xor(v, m);
  return v;
}

DEV unsigned short bf16rne(float f){
  unsigned int u = __float_as_uint(f);
  u += 0x7FFFu + ((u >> 16) & 1u);
  return (unsigned short)(u >> 16);
}
DEV float bf16tof(unsigned short h){ return __uint_as_float(((unsigned int)h) << 16); }

// sk' = min(sk, max(bk, k)) given bk<=sk  ==  median(sk, bk, k), one VALU op.
DEV unsigned umed3(unsigned a, unsigned b, unsigned c){
  unsigned d;
  asm("v_med3_u32 %0, %1, %2, %3" : "=v"(d) : "v"(a), "v"(b), "v"(c));
  return d;
}

// ---- stats layout (float offsets within stats block) ----
#define S1 0
#define Q1 16
#define S2 32
#define Q2 64
#define S3 96
#define Q3 160
#define S4 224
#define Q4 288
#define S5 352
#define Q5 416
#define SLOSS 480
#define CNTOFF 500
#define NSTATF 512

#define EPSQ 6u
#define NCHUNK 8

// =========================================================================
// K_prep: enc_w3 -> w3t [(i*25+k)*64+c] (f32, c-coalesced); dec_wt -> wb7.
__global__ void k_prep(const float* ew3, const float* dwt, float* w3t,
                       unsigned short* wb7){
  const int n1 = 64*32*25, n2 = 64*64*25;
  for(int i = blockIdx.x*blockDim.x + threadIdx.x; i < n1+n2; i += gridDim.x*blockDim.x){
    if(i < n1){
      int c = i/(32*25), r = i - c*(32*25), ii = r/25, k = r - ii*25;
      w3t[(ii*25 + k)*64 + c] = ew3[i];
    } else {
      int j = i - n1;
      int ii = j/(64*25), r = j - ii*(64*25), o = r/25, k = r - o*25;
      wb7[((size_t)(k*64 + o))*64 + ii] = bf16rne(dwt[j]);
    }
  }
}

// =========================================================================
// K_prep2: codebook -> pre-swizzled bf16 hi/lo rows + norms + plain bf16 cbb.
__global__ void k_prep2(const float* __restrict__ cb, unsigned short* __restrict__ cbsw,
                        float* __restrict__ cnw, float* __restrict__ cnw2,
                        unsigned short* __restrict__ cbb){
  int j = blockIdx.x*256 + threadIdx.x;
  if(j < 8192){
    float nrm = 0.f;
    unsigned swz = (j & 15) << 4;
    char* rowp = (char*)cbsw + (size_t)j*256;
    #pragma unroll
    for(int k = 0; k < 64; k++){
      float x = cb[(size_t)j*64 + k];
      unsigned short hi = bf16rne(x);
      float lo = x - bf16tof(hi);
      *(unsigned short*)(rowp + (((unsigned)(2*k)) ^ swz)) = hi;
      *(unsigned short*)(rowp + (((unsigned)(128 + 2*k)) ^ swz)) = bf16rne(lo);
      cbb[(size_t)j*64 + k] = hi;
      nrm = fmaf(x, x, nrm);
    }
    cnw[j] = nrm;
    cnw2[j] = (nrm + 1024.f) * 256.f;
  }
}

// =========================================================================
// K1: conv1 (1->16, K=5, pad2) + silu + bn1 stats.
__global__ void k1(const float* __restrict__ x, const float* __restrict__ w1,
                   const float* __restrict__ b1, float* __restrict__ h1, float* stats){
  __shared__ float xs[136];
  __shared__ float ssum[16], ssq[16];
  int tid = threadIdx.x, b = blockIdx.y, t0 = blockIdx.x*128;
  if(tid < 16){ ssum[tid] = 0.f; ssq[tid] = 0.f; }
  for(int i = tid; i < 132; i += 256){
    int t = t0 + i - 2;
    xs[i] = (t >= 0 && t < 10240) ? x[b*10240 + t] : 0.f;
  }
  __syncthreads();
  int c = tid & 15, sgrp = tid >> 4;
  float w[5];
  #pragma unroll
  for(int k = 0; k < 5; k++) w[k] = w1[c*5 + k];
  float bias = b1[c];
  float outv[8];
  float ps = 0.f, pq = 0.f;
  #pragma unroll
  for(int s = 0; s < 8; s++){
    float a = bias;
    #pragma unroll
    for(int k = 0; k < 5; k++) a = fmaf(w[k], xs[sgrp*8 + s + k], a);
    a = siluf(a);
    outv[s] = a;
    ps += a; pq += a*a;
  }
  float* op = h1 + ((size_t)(b*16 + c))*10240 + t0 + sgrp*8;
  #pragma unroll
  for(int q = 0; q < 2; q++)
    *(float4*)(op + q*4) = make_float4(outv[q*4], outv[q*4+1], outv[q*4+2], outv[q*4+3]);
  ps += __shfl_xor(ps, 16); pq += __shfl_xor(pq, 16);
  ps += __shfl_xor(ps, 32); pq += __shfl_xor(pq, 32);
  if((tid & 48) == 0){ atomicAdd(&ssum[c], ps); atomicAdd(&ssq[c], pq); }
  __syncthreads();
  if(tid < 16){ atomicAdd(stats+S1+tid, ssum[tid]); atomicAdd(stats+Q1+tid, ssq[tid]); }
}

// =========================================================================
// K2: bn1 normalize + conv2 (16->32, K=5, pad2) + silu + bn2 stats.
__global__ __launch_bounds__(256) void k2(const float* __restrict__ h1,
                   const float* __restrict__ w2, const float* __restrict__ b2,
                   const float* __restrict__ g1, const float* __restrict__ bb1,
                   float* __restrict__ h2out, float* stats){
  __shared__ float hs[16][136];
  __shared__ float A1s[16], B1s[16];
  __shared__ float ssum[32], ssq[32];
  int tid = threadIdx.x, b = blockIdx.y, t0 = blockIdx.x*128;
  if(tid < 16){
    float mu = stats[S1+tid]/81920.f;
    float var = stats[Q1+tid]/81920.f - mu*mu;
    float rs = rsqrtf(var + 1e-5f);
    A1s[tid] = rs*g1[tid];
    B1s[tid] = bb1[tid] - mu*rs*g1[tid];
  }
  if(tid < 32){ ssum[tid] = 0.f; ssq[tid] = 0.f; }
  __syncthreads();
  {
    int ch = tid >> 4, j0 = tid & 15;
    float A = A1s[ch], B = B1s[ch];
    const float* hp = h1 + ((size_t)(b*16 + ch))*10240;
    for(int j = j0; j < 132; j += 16){
      int t = t0 + j - 2;
      hs[ch][j] = (t >= 0 && t < 10240) ? hp[t]*A + B : 0.f;
    }
  }
  __syncthreads();
  int c = tid & 31, tgrp = tid >> 5;
  int tb = tgrp*16;
  float acc[16];
  float bias = b2[c];
  #pragma unroll
  for(int s = 0; s < 16; s++) acc[s] = bias;
  for(int ic = 0; ic < 4; ic++){
    float wf[20];
    const float* wp = w2 + c*80 + ic*20;
    #pragma unroll
    for(int q = 0; q < 5; q++) *(float4*)(wf + q*4) = *(const float4*)(wp + q*4);
    #pragma unroll
    for(int di = 0; di < 4; di++){
      int i = ic*4 + di;
      float z[20];
      #pragma unroll
      for(int q = 0; q < 5; q++) *(float4*)(z + q*4) = *(const float4*)(&hs[i][tb] + q*4);
      float w0 = wf[di*5], w1 = wf[di*5+1], w2v = wf[di*5+2], w3 = wf[di*5+3], w4 = wf[di*5+4];
      #pragma unroll
      for(int s = 0; s < 16; s++)
        acc[s] = fmaf(w0, z[s], fmaf(w1, z[s+1], fmaf(w2v, z[s+2],
                 fmaf(w3, z[s+3], fmaf(w4, z[s+4], acc[s])))));
    }
  }
  float ps = 0.f, pq = 0.f;
  #pragma unroll
  for(int s = 0; s < 16; s++){
    float a = siluf(acc[s]);
    acc[s] = a;
    ps += a; pq += a*a;
  }
  float* op = h2out + ((size_t)(b*32 + c))*10240 + t0 + tb;
  #pragma unroll
  for(int q = 0; q < 4; q++)
    *(float4*)(op + q*4) = make_float4(acc[q*4], acc[q*4+1], acc[q*4+2], acc[q*4+3]);
  ps += __shfl_xor(ps, 32); pq += __shfl_xor(pq, 32);
  if((tid & 32) == 0){ atomicAdd(&ssum[c], ps); atomicAdd(&ssq[c], pq); }
  __syncthreads();
  if(tid < 32){ atomicAdd(stats+S2+tid, ssum[tid]); atomicAdd(stats+Q2+tid, ssq[tid]); }
}

// =========================================================================
// K3 v6: round-11 structure + weight panel LDS staging (double-buffered
// gl_lds, 6.4KB per i). Weight values and FMA order identical -> zn bitwise
// identical to round-16. Weight ds_read: lane-consecutive c -> conflict-free.
__global__ __launch_bounds__(256) void k3(const float* __restrict__ h2,
                   const float* __restrict__ w3t,
                   const float* __restrict__ eb3, const float* __restrict__ g2,
                   const float* __restrict__ bb2, float* __restrict__ zn, float* stats){
  __shared__ __align__(16) float X[5*32*24];   // [kk][ch][m], m<20 valid
  __shared__ __align__(16) float Wl[2][1600];  // [(kap*5+kk)*64 + c] per i
  __shared__ float A2[32], B2[32];
  __shared__ float ssum[64], ssq[64];
  int tid = threadIdx.x, b = blockIdx.y, l0 = blockIdx.x*16;
  if(tid < 32){
    float mu = stats[S2+tid]/81920.f;
    float var = stats[Q2+tid]/81920.f - mu*mu;
    float rs = rsqrtf(var + 1e-5f);
    A2[tid] = rs*g2[tid];
    B2[tid] = bb2[tid] - mu*rs*g2[tid];
  }
  if(tid < 64){ ssum[tid] = 0.f; ssq[tid] = 0.f; }
  // issue weight stage for i=0 (async; drained by the barrier after X staging)
  for(int o = tid; o < 400; o += 256)
    gl_lds((const char*)w3t + o*16, (char*)&Wl[0][0] + o*16);
  __syncthreads();   // A2/B2 visible for X staging
  for(int i2 = tid; i2 < 5*32*20; i2 += 256){
    int kk = i2/640;
    int r  = i2 - kk*640;
    int ch = r/20, m = r - ch*20;
    int t = 5*(l0 + m) + kk - 12;
    float v = 0.f;
    if(t >= 0 && t < 10240) v = h2[((b*32+ch)*10240)+t]*A2[ch] + B2[ch];
    X[(kk*32+ch)*24 + m] = v;
  }
  __syncthreads();   // X ready; Wl[0] gl_lds drained
  int c = tid & 63, lslot = tid >> 6;   // 4 waves x 4 l
  float acc[4];
  float bias = eb3[c];
  #pragma unroll
  for(int s = 0; s < 4; s++) acc[s] = bias;
  int cur = 0;
  for(int i = 0; i < 32; i++){
    if(i < 31){
      const char* src = (const char*)w3t + (size_t)(i+1)*6400;
      for(int o = tid; o < 400; o += 256)
        gl_lds(src + o*16, (char*)&Wl[cur^1][0] + o*16);
    }
    #pragma unroll
    for(int kk = 0; kk < 5; kk++){
      const float* xp = &X[(kk*32+i)*24 + lslot*4];
      float4 za = *(const float4*)(xp);
      float4 zb = *(const float4*)(xp + 4);
      float z[8] = {za.x,za.y,za.z,za.w,zb.x,zb.y,zb.z,zb.w};
      #pragma unroll
      for(int kap = 0; kap < 5; kap++){
        float w = Wl[cur][(kap*5 + kk)*64 + c];
        #pragma unroll
        for(int s = 0; s < 4; s++) acc[s] = fmaf(w, z[s+kap], acc[s]);
      }
    }
    __syncthreads();   // next panel staged & everyone done with cur
    cur ^= 1;
  }
  float ls = 0.f, lq = 0.f;
  #pragma unroll
  for(int s = 0; s < 4; s++){
    int l = l0 + lslot*4 + s;
    float a = tanhf(acc[s]);
    zn[((b*2048 + l)*64) + c] = a;
    ls += a; lq += a*a;
  }
  atomicAdd(&ssum[c], ls); atomicAdd(&ssq[c], lq);
  __syncthreads();
  if(tid < 64){ atomicAdd(stats+S3+tid, ssum[tid]); atomicAdd(stats+Q3+tid, ssq[tid]); }
}

// =========================================================================
// K5m: MFMA VQ pass (merged accumulator, (256,4)).
__global__ __launch_bounds__(256, 4) void k5m(const float* __restrict__ zn,
    const unsigned short* __restrict__ cbsw, const float* __restrict__ cnw2,
    const float* __restrict__ g3, const float* __restrict__ b3,
    const float* __restrict__ stats,
    unsigned int* __restrict__ pbk, unsigned int* __restrict__ psk){
  __shared__ __align__(16) unsigned char cbuf[2][16384];
  __shared__ float A3s[64], B3s[64];
  int tid = threadIdx.x;
  int chunk = blockIdx.x;
  int m0 = blockIdx.y * 128;
  int lane = tid & 63, wr = tid >> 6;
  int h = lane >> 5, cll = lane & 31;
  int row = m0 + wr*32 + cll;

  if(tid < 64){
    float mu = stats[S3+tid]/16384.f;
    float var = stats[Q3+tid]/16384.f - mu*mu;
    float rs = rsqrtf(var + 1e-5f);
    A3s[tid] = rs*g3[tid];
    B3s[tid] = b3[tid] - mu*rs*g3[tid];
  }

  int c0 = chunk * 1024;
  const char* csrc = (const char*)cbsw + (size_t)c0*256;
  #pragma unroll
  for(int c2 = 0; c2 < 4; c2++)
    gl_lds(csrc + c2*4096 + tid*16, &cbuf[0][0] + c2*4096 + tid*16);
  __syncthreads();

  s8v ah[4], al[4];
  const float* zp = zn + (size_t)row*64;
  #pragma unroll
  for(int s = 0; s < 4; s++){
    int koff = s*16 + h*8;
    float4 v0 = *(const float4*)(zp + koff);
    float4 v1 = *(const float4*)(zp + koff + 4);
    float vv[8] = {v0.x,v0.y,v0.z,v0.w,v1.x,v1.y,v1.z,v1.w};
    #pragma unroll
    for(int i = 0; i < 8; i++){
      float v = fmaf(vv[i], A3s[koff + i], B3s[koff + i]);
      unsigned short hi = bf16rne(v);
      ah[s][i] = (short)hi;
      al[s][i] = (short)bf16rne(v - bf16tof(hi));
    }
  }

  unsigned int bk[16], sk[16];
  #pragma unroll
  for(int r = 0; r < 16; r++){ bk[r] = 0xFFFFFFFFu; sk[r] = 0xFFFFFFFFu; }
  f32x16 zv;
  #pragma unroll
  for(int i = 0; i < 16; i++) zv[i] = 0.f;

  unsigned swz = (unsigned)(cll & 15) << 4;
  for(int tile = 0; tile < 16; ++tile){
    int bsel = tile & 1;
    if(tile < 15){
      const char* ns = csrc + (size_t)(tile+1)*16384;
      #pragma unroll
      for(int c2 = 0; c2 < 4; c2++)
        gl_lds(ns + c2*4096 + tid*16, &cbuf[bsel^1][0] + c2*4096 + tid*16);
    }
    #pragma unroll
    for(int half = 0; half < 2; half++){
      const unsigned char* bp = &cbuf[bsel][0] + (half*32 + cll)*256;
      s8v bh[4], bl[4];
      #pragma unroll
      for(int s = 0; s < 4; s++){
        bh[s] = *(const s8v*)(bp + (((unsigned)(s*32 + h*16)) ^ swz));
        bl[s] = *(const s8v*)(bp + (((unsigned)(128 + s*32 + h*16)) ^ swz));
      }
      unsigned col = (unsigned)(c0 + tile*64 + half*32 + cll);
      float cnv2 = cnw2[col];
      f32x16 a = __builtin_amdgcn_mfma_f32_32x32x16_bf16(ah[0], bl[0], zv, 0, 0, 0);
      a = __builtin_amdgcn_mfma_f32_32x32x16_bf16(al[0], bh[0], a, 0, 0, 0);
      a = __builtin_amdgcn_mfma_f32_32x32x16_bf16(ah[0], bh[0], a, 0, 0, 0);
      #pragma unroll
      for(int s = 1; s < 4; s++){
        a = __builtin_amdgcn_mfma_f32_32x32x16_bf16(ah[s], bl[s], a, 0, 0, 0);
        a = __builtin_amdgcn_mfma_f32_32x32x16_bf16(al[s], bh[s], a, 0, 0, 0);
        a = __builtin_amdgcn_mfma_f32_32x32x16_bf16(ah[s], bh[s], a, 0, 0, 0);
      }
      #pragma unroll
      for(int r = 0; r < 16; r++){
        float q = fmaf(-512.f, a[r], cnv2);
        q = fminf(q, 524287.f);
        unsigned k = (((unsigned)q) << 13) | col;
        unsigned nb = bk[r] < k ? bk[r] : k;
        sk[r] = umed3(sk[r], bk[r], k);
        bk[r] = nb;
      }
    }
    __syncthreads();
  }

  #pragma unroll
  for(int m = 1; m <= 16; m <<= 1){
    #pragma unroll
    for(int r = 0; r < 16; r++){
      unsigned int ob = (unsigned int)__shfl_xor((int)bk[r], m);
      unsigned int os = (unsigned int)__shfl_xor((int)sk[r], m);
      unsigned int s2 = sk[r] < os ? sk[r] : os;
      sk[r] = umed3(s2, bk[r], ob);
      bk[r] = bk[r] < ob ? bk[r] : ob;
    }
  }
  if(cll == 0){
    size_t base = (size_t)chunk*16384 + m0 + wr*32 + 4*h;
    #pragma unroll
    for(int r = 0; r < 16; r++){
      int lr = (r&3) + 8*(r>>2);
      pbk[base + lr] = bk[r];
      psk[base + lr] = sk[r];
    }
  }
}

// =========================================================================
// K5r: merge chunk partials; write idx; flag close calls.
__global__ void k5r(const unsigned int* __restrict__ pbk,
                    const unsigned int* __restrict__ psk, int* __restrict__ idxw,
                    float* __restrict__ out_idx, int* __restrict__ list, int* cnt){
  int row = blockIdx.x*256 + threadIdx.x;  // grid 64
  unsigned int bk = pbk[row], sk = psk[row];
  #pragma unroll
  for(int c = 1; c < NCHUNK; c++){
    unsigned int ob = pbk[(size_t)c*16384 + row];
    unsigned int os = psk[(size_t)c*16384 + row];
    unsigned int s2 = sk < os ? sk : os;
    sk = umed3(s2, bk, ob);
    bk = bk < ob ? bk : ob;
  }
  int idx = (int)(bk & 0x1FFFu);
  idxw[row] = idx;
  out_idx[row] = (float)idx;
  if((sk >> 13) - (bk >> 13) <= EPSQ){
    int p = atomicAdd(cnt, 1);
    list[p] = row;
  }
}

// =========================================================================
// K5x: exact f32 rescore, row-parallel; bn3 affine applied on z-row load.
__global__ __launch_bounds__(256) void k5x(const float* __restrict__ zn,
    const float* __restrict__ cb, const float* __restrict__ cnw,
    const float* __restrict__ g3, const float* __restrict__ b3,
    const float* __restrict__ stats,
    const int* __restrict__ list, const int* cnt,
    float* __restrict__ pxd, int* __restrict__ pxi){
  __shared__ float A3s[64], B3s[64];
  int tid = threadIdx.x;
  if(tid < 64){
    float mu = stats[S3+tid]/16384.f;
    float var = stats[Q3+tid]/16384.f - mu*mu;
    float rs = rsqrtf(var + 1e-5f);
    A3s[tid] = rs*g3[tid];
    B3s[tid] = b3[tid] - mu*rs*g3[tid];
  }
  __syncthreads();
  int chunk = blockIdx.x;
  int n = *cnt;
  int rgrp = tid >> 6, cs = tid & 63;
  int c0 = chunk * 1024;
  for(int bat = blockIdx.y; bat*4 < n; bat += 256){
    int e = bat*4 + rgrp;
    int ec = e < n ? e : n-1;
    int row = list[ec];
    float4 zr[16];
    const float4* zp = (const float4*)(zn + (size_t)row*64);
    #pragma unroll
    for(int q = 0; q < 16; q++){
      float4 v = zp[q];
      v.x = fmaf(v.x, A3s[q*4+0], B3s[q*4+0]);
      v.y = fmaf(v.y, A3s[q*4+1], B3s[q*4+1]);
      v.z = fmaf(v.z, A3s[q*4+2], B3s[q*4+2]);
      v.w = fmaf(v.w, A3s[q*4+3], B3s[q*4+3]);
      zr[q] = v;
    }
    float bd = 3.4e38f; int bi = 0;
    for(int step = 0; step < 16; step++){
      int j = c0 + step*64 + cs;
      const float4* cp = (const float4*)(cb + (size_t)j*64);
      float cnv = cnw[j];
      float da = 0.f, db = 0.f;
      #pragma unroll
      for(int q = 0; q < 16; q += 2){
        float4 ca = cp[q], cb4 = cp[q+1];
        da = fmaf(ca.x, zr[q].x, da);  da = fmaf(ca.y, zr[q].y, da);
        da = fmaf(ca.z, zr[q].z, da);  da = fmaf(ca.w, zr[q].w, da);
        db = fmaf(cb4.x, zr[q+1].x, db); db = fmaf(cb4.y, zr[q+1].y, db);
        db = fmaf(cb4.z, zr[q+1].z, db); db = fmaf(cb4.w, zr[q+1].w, db);
      }
      float d = fmaf(-2.f, da + db, cnv);
      if(d < bd){ bd = d; bi = j; }
    }
    #pragma unroll
    for(int m = 1; m <= 32; m <<= 1){
      float od = __shfl_xor(bd, m);
      int   oi = __shfl_xor(bi, m);
      if(od < bd || (od == bd && oi < bi)){ bd = od; bi = oi; }
    }
    if(cs == 0 && e < n){
      pxd[(size_t)chunk*16384 + e] = bd;
      pxi[(size_t)chunk*16384 + e] = bi;
    }
  }
}

// =========================================================================
// K5x2: merge chunk partials per flagged row -> final idx.
__global__ void k5x2(const float* __restrict__ pxd, const int* __restrict__ pxi,
                     const int* __restrict__ list, const int* cnt,
                     int* __restrict__ idxw, float* __restrict__ out_idx){
  int e = blockIdx.x*256 + threadIdx.x;  // grid 64
  int n = *cnt;
  if(e >= n) return;
  float bd = pxd[e]; int bi = pxi[e];
  #pragma unroll
  for(int c = 1; c < NCHUNK; c++){
    float od = pxd[(size_t)c*16384 + e];
    int   oi = pxi[(size_t)c*16384 + e];
    if(od < bd || (od == bd && oi < bi)){ bd = od; bi = oi; }
  }
  int row = list[e];
  idxw[row] = bi;
  out_idx[row] = (float)bi;
}

// =========================================================================
// K_loss: commit loss from final indices; bn3 affine applied on z load.
__global__ void k_loss(const float* __restrict__ zn, const float* __restrict__ cb,
                       const float* __restrict__ g3, const float* __restrict__ b3,
                       const int* __restrict__ idxw, float* stats){
  __shared__ float A3s[64], B3s[64];
  int tid = threadIdx.x;
  if(tid < 64){
    float mu = stats[S3+tid]/16384.f;
    float var = stats[Q3+tid]/16384.f - mu*mu;
    float rs = rsqrtf(var + 1e-5f);
    A3s[tid] = rs*g3[tid];
    B3s[tid] = b3[tid] - mu*rs*g3[tid];
  }
  __syncthreads();
  int row = blockIdx.x*256 + tid;  // grid 64
  int code = idxw[row];
  const float* cp = cb + (size_t)code*64;
  const float* zp = zn + (size_t)row*64;
  float s = 0.f;
  #pragma unroll
  for(int k = 0; k < 64; k++){
    float v = fmaf(zp[k], A3s[k], B3s[k]);
    float dd = cp[k] - v;
    s = fmaf(dd, dd, s);
  }
  float tot = wredsum(s);
  if((tid & 63) == 0) atomicAdd(stats + SLOSS, tot);
}

// =========================================================================
// K7m: transposed conv as MFMA GEMM.
__global__ __launch_bounds__(320) void k7m(const int* __restrict__ idxp,
    const unsigned short* __restrict__ cbb, const unsigned short* __restrict__ wb7,
    unsigned short* __restrict__ h4t, float* stats){
  __shared__ __align__(16) unsigned char lA[37*128];
  __shared__ float tb[5*64*33];
  __shared__ float ssum[64], ssq[64];
  int tid = threadIdx.x, b = blockIdx.y, u0 = blockIdx.x*32;
  if(tid < 64){ ssum[tid] = 0.f; ssq[tid] = 0.f; }
  {
    int m = tid >> 3, part = tid & 7;
    if(m < 37){
      int u = u0 - 2 + m;
      uint4 val = make_uint4(0,0,0,0);
      if(u >= 0 && u < 2048){
        int code = idxp[b*2048 + u];
        val = *(const uint4*)((const char*)cbb + (size_t)code*128 + part*16);
      }
      *(uint4*)(lA + m*128 + (((unsigned)(part*16)) ^ (((unsigned)m & 7) << 4))) = val;
    }
  }
  __syncthreads();
  int lane = tid & 63, h = lane >> 5, cl = lane & 31;
  int v = tid >> 6;
  const int km[5]  = {2,3,4,0,1};
  const int ovv[5] = {2,2,2,3,3};
  f32x16 acc0, acc1;
  #pragma unroll
  for(int i = 0; i < 16; i++){ acc0[i] = 0.f; acc1[i] = 0.f; }
  #pragma unroll
  for(int r = 0; r < 5; r++){
    int off = ovv[v] - r + 2;
    int m = cl + off;
    unsigned aswz = ((unsigned)m & 7) << 4;
    int k = km[v] + 5*r;
    const char* b0p = (const char*)wb7 + (size_t)(k*64 + cl)*128;
    const char* b1p = b0p + 32*128;
    #pragma unroll
    for(int s = 0; s < 4; s++){
      unsigned o = (unsigned)(s*32 + h*16);
      s8v a  = *(const s8v*)(lA + m*128 + (o ^ aswz));
      s8v b0 = *(const s8v*)(b0p + o);
      s8v b1 = *(const s8v*)(b1p + o);
      acc0 = __builtin_amdgcn_mfma_f32_32x32x16_bf16(a, b0, acc0, 0, 0, 0);
      acc1 = __builtin_amdgcn_mfma_f32_32x32x16_bf16(a, b1, acc1, 0, 0, 0);
    }
  }
  float ps0 = 0.f, pq0 = 0.f, ps1 = 0.f, pq1 = 0.f;
  #pragma unroll
  for(int r = 0; r < 16; r++){
    int ul = (r&3) + 8*(r>>2) + 4*h;
    int u = u0 + ul;
    float v0 = siluf(acc0[r]), v1 = siluf(acc1[r]);
    tb[(v*64 + cl)*33 + ul]      = v0;
    tb[(v*64 + 32 + cl)*33 + ul] = v1;
    if(v == 0 || u < 2047){ ps0 += v0; pq0 += v0*v0; ps1 += v1; pq1 += v1*v1; }
  }
  atomicAdd(&ssum[cl], ps0);      atomicAdd(&ssq[cl], pq0);
  atomicAdd(&ssum[32 + cl], ps1); atomicAdd(&ssq[32 + cl], pq1);
  __syncthreads();
  if(tid < 64){ atomicAdd(stats+S4+tid, ssum[tid]); atomicAdd(stats+Q4+tid, ssq[tid]); }
  #pragma unroll
  for(int j = 0; j < 16; j++){
    int flat = j*320 + tid;
    int tl = flat >> 5;
    int chp = flat & 31;
    int t = u0*5 + tl;
    if(t < 10236){
      int vv = tl % 5, ul = tl / 5;
      float f0 = tb[(vv*64 + 2*chp)*33 + ul];
      float f1 = tb[(vv*64 + 2*chp + 1)*33 + ul];
      unsigned int pk = (unsigned int)bf16rne(f0) | ((unsigned int)bf16rne(f1) << 16);
      size_t rowb = ((size_t)b*10248 + 2 + t)*128;
      *(unsigned int*)((char*)h4t + rowb + (((unsigned)(4*chp)) ^ (((unsigned)t & 7) << 4))) = pk;
    }
  }
}

// =========================================================================
// K8w: fold dbn1 into decoder conv2 weights + beta; also zero h4t pad rows.
__global__ void k8w(const float* __restrict__ w2d, const float* __restrict__ b2d,
                    const float* __restrict__ g4, const float* __restrict__ bb4,
                    const float* __restrict__ stats, unsigned short* __restrict__ wbt,
                    float* __restrict__ beta, unsigned int* __restrict__ h4tz){
  __shared__ float A4[64], B4[64];
  int tid = threadIdx.x;
  for(int i = tid; i < 3072; i += 256){
    int b = i / 384, r = i - b*384;
    int row12 = r >> 5, word = r & 31;
    int row = row12 < 2 ? row12 : 10236 + row12;
    h4tz[((size_t)b*10248 + row)*32 + word] = 0u;
  }
  if(tid < 64){
    float mu = stats[S4+tid]/81888.f;
    float var = stats[Q4+tid]/81888.f - mu*mu;
    float rs = rsqrtf(var + 1e-5f);
    A4[tid] = rs*g4[tid];
    B4[tid] = bb4[tid] - mu*rs*g4[tid];
  }
  __syncthreads();
  for(int e = tid; e < 64*64*5; e += 256){
    int c = e/320, r = e - c*320, i = r/5, k = r - i*5;
    unsigned short hw = bf16rne(w2d[e] * A4[i]);
    int row = k*64 + c;
    *(unsigned short*)((char*)wbt + (size_t)row*128 + (((unsigned)(2*i)) ^ (((unsigned)c & 7) << 4))) = hw;
  }
  if(tid < 64){
    float s = b2d[tid];
    for(int i = 0; i < 64; i++){
      float wsum = 0.f;
      #pragma unroll
      for(int k = 0; k < 5; k++) wsum += w2d[(tid*64 + i)*5 + k];
      s += wsum * B4[i];
    }
    beta[tid] = s;
  }
}

// =========================================================================
// K8: decoder conv2 as MFMA GEMM.
__global__ __launch_bounds__(256) void k8(const unsigned short* __restrict__ h4t,
    const unsigned short* __restrict__ wbt, const float* __restrict__ beta,
    unsigned short* __restrict__ h5b, float* stats){
  __shared__ __align__(16) unsigned char lA[68*128];
  __shared__ float ssum[64], ssq[64];
  int tid = threadIdx.x, b = blockIdx.y, t0 = blockIdx.x*64;
  if(tid < 64){ ssum[tid] = 0.f; ssq[tid] = 0.f; }
  const char* srcA = (const char*)h4t + ((size_t)b*10248 + t0)*128;
  #pragma unroll
  for(int c2 = 0; c2 < 2; c2++)
    gl_lds(srcA + c2*4096 + tid*16, lA + c2*4096 + tid*16);
  if(tid < 32) gl_lds(srcA + 8192 + tid*16, lA + 8192 + tid*16);
  __syncthreads();

  int lane = tid & 63, h = lane >> 5, cl = lane & 31;
  int widx = tid >> 6;
  int wt0 = (widx >> 1) * 32;
  int wch = (widx & 1) * 32;
  f32x16 acc;
  #pragma unroll
  for(int i = 0; i < 16; i++) acc[i] = 0.f;
  unsigned bswz = (unsigned)(cl & 7) << 4;
  #pragma unroll
  for(int k = 0; k < 5; k++){
    int l = wt0 + cl + k;
    unsigned aswz = (unsigned)((l + 6) & 7) << 4;
    const char* bp = (const char*)wbt + (size_t)(k*64 + wch + cl)*128;
    #pragma unroll
    for(int s = 0; s < 4; s++){
      unsigned o = (unsigned)(s*32 + h*16);
      s8v a  = *(const s8v*)(lA + l*128 + (o ^ aswz));
      s8v bb = *(const s8v*)(bp + (o ^ bswz));
      acc = __builtin_amdgcn_mfma_f32_32x32x16_bf16(a, bb, acc, 0, 0, 0);
    }
  }
  float bet = beta[wch + cl];
  float ps = 0.f, pq = 0.f;
  #pragma unroll
  for(int r = 0; r < 16; r++){
    int t = t0 + wt0 + (r&3) + 8*(r>>2) + 4*h;
    float v0 = siluf(acc[r] + bet);
    if(t < 10236){
      h5b[((size_t)b*10240 + t)*64 + wch + cl] = bf16rne(v0);
      ps += v0; pq += v0*v0;
    }
  }
  atomicAdd(&ssum[wch + cl], ps); atomicAdd(&ssq[wch + cl], pq);
  __syncthreads();
  if(tid < 64){ atomicAdd(stats+S5+tid, ssum[tid]); atomicAdd(stats+Q5+tid, ssq[tid]); }
}

// =========================================================================
// K9: dbn2 normalize + 1x1 conv (64->1) + bias; also writes commit loss.
__global__ void k9(const unsigned short* __restrict__ h5b, const float* __restrict__ w3,
                   const float* __restrict__ b3, const float* __restrict__ g5,
                   const float* __restrict__ bb5, const float* stats,
                   float* __restrict__ out){
  __shared__ float WA[64], WB[64];
  int tid = threadIdx.x;
  if(blockIdx.x == 0 && blockIdx.y == 0 && tid == 0)
    out[98304] = 2.f * stats[SLOSS] / 1048576.f;
  if(tid < 64){
    float mu = stats[S5+tid]/81888.f;
    float var = stats[Q5+tid]/81888.f - mu*mu;
    float rs = rsqrtf(var + 1e-5f);
    float A = rs*g5[tid], B = bb5[tid] - mu*rs*g5[tid];
    float w = w3[tid];
    WA[tid] = w*A; WB[tid] = w*B;
  }
  __syncthreads();
  int b = blockIdx.y;
  int t = blockIdx.x*256 + tid;
  float acc = b3[0];
  if(t < 10236){
    const unsigned short* hp = h5b + ((size_t)b*10240 + t)*64;
    #pragma unroll
    for(int q = 0; q < 8; q++){
      uint4 u = *(const uint4*)(hp + q*8);
      unsigned int ua[4] = {u.x, u.y, u.z, u.w};
      #pragma unroll
      for(int w = 0; w < 4; w++){
        int c = q*8 + w*2;
        acc += WA[c]*bf16tof((unsigned short)(ua[w] & 0xFFFFu)) + WB[c];
        acc += WA[c+1]*bf16tof((unsigned short)(ua[w] >> 16)) + WB[c+1];
      }
    }
  } else acc = 0.f;
  out[b*10240 + t] = acc;
}

// =========================================================================
extern "C" void kernel_launch(void* const* d_in, const int* in_sizes, int n_in,
                              void* d_out, int out_size, void* d_ws, size_t ws_size,
                              hipStream_t stream){
  const float* x   = (const float*)d_in[0];
  const float* ew1 = (const float*)d_in[1];
  const float* eb1 = (const float*)d_in[2];
  const float* g1  = (const float*)d_in[3];
  const float* bb1 = (const float*)d_in[4];
  const float* ew2 = (const float*)d_in[5];
  const float* eb2 = (const float*)d_in[6];
  const float* g2  = (const float*)d_in[7];
  const float* bb2 = (const float*)d_in[8];
  const float* ew3 = (const float*)d_in[9];
  const float* eb3 = (const float*)d_in[10];
  const float* g3  = (const float*)d_in[11];
  const float* bb3 = (const float*)d_in[12];
  const float* cb  = (const float*)d_in[13];
  const float* dwt = (const float*)d_in[14];
  const float* g4  = (const float*)d_in[15];
  const float* bb4 = (const float*)d_in[16];
  const float* w2d = (const float*)d_in[17];
  const float* b2d = (const float*)d_in[18];
  const float* g5  = (const float*)d_in[19];
  const float* bb5 = (const float*)d_in[20];
  const float* w3d = (const float*)d_in[21];
  const float* b3d = (const float*)d_in[22];

  char* ws = (char*)d_ws;
  float* h1   = (float*)(ws + 0);
  unsigned short* cbsw = (unsigned short*)(ws + 0);         // 2,097,152
  float* cnw  = (float*)(ws + 2097152);                     // 32,768
  float* cnw2 = (float*)(ws + 2129920);                     // 32,768
  float* h2   = (float*)(ws + 5242880);
  float* zn   = (float*)(ws + 15728640);
  unsigned short* h4t = (unsigned short*)(ws + 0);          // 10,493,952 (k7m+)
  unsigned short* h5b = (unsigned short*)(ws + 20971520);   // 10,485,760 (k8+)
  int*   list = (int*)  (ws + 20971520);                    // 65,536 (k5r+, pre-k7m)
  unsigned int* pbk = (unsigned int*)(ws + 21037312);       // 524,288 (k5m+)
  unsigned int* psk = (unsigned int*)(ws + 21561600);       // 524,288
  float* pxd  = (float*)(ws + 22085888);                    // 524,288 (k5x+)
  int*   pxi  = (int*)  (ws + 22610176);                    // 524,288
  unsigned short* wbt = (unsigned short*)(ws + 31457280);   // 40,960 (k8w+)
  float* beta = (float*)(ws + 31498240);                    // 256
  unsigned short* wb7 = (unsigned short*)(ws + 32000000);   // 204,800
  unsigned short* cbb = (unsigned short*)(ws + 32300032);   // 1,048,576
  float* w3t  = (float*)(ws + 33400000);                    // 204,800
  int*   idxw = (int*)  (ws + 42549248);
  float* stats= (float*)(ws + 42614784);
  int*   cnt  = (int*)(stats + CNTOFF);                     // inside memset-zeroed stats
  if(ws_size < 42616832) return;

  float* out = (float*)d_out;  // f32: [recon 81920][idx 16384][loss 1]

  hipMemsetAsync(stats, 0, NSTATF*4, stream);
  k_prep<<<600, 256, 0, stream>>>(ew3, dwt, w3t, wb7);
  k1<<<dim3(80,8), 256, 0, stream>>>(x, ew1, eb1, h1, stats);
  k2<<<dim3(80,8), 256, 0, stream>>>(h1, ew2, eb2, g1, bb1, h2, stats);
  k_prep2<<<32, 256, 0, stream>>>(cb, cbsw, cnw, cnw2, cbb);
  k3<<<dim3(128,8), 256, 0, stream>>>(h2, w3t, eb3, g2, bb2, zn, stats);
  k5m<<<dim3(NCHUNK,128), 256, 0, stream>>>(zn, cbsw, cnw2, g3, bb3, stats, pbk, psk);
  k5r<<<64, 256, 0, stream>>>(pbk, psk, idxw, out + 81920, list, cnt);
  k5x<<<dim3(NCHUNK,256), 256, 0, stream>>>(zn, cb, cnw, g3, bb3, stats, list, cnt, pxd, pxi);
  k5x2<<<64, 256, 0, stream>>>(pxd, pxi, list, cnt, idxw, out + 81920);
  k_loss<<<64, 256, 0, stream>>>(zn, cb, g3, bb3, idxw, stats);
  k7m<<<dim3(64,8), 320, 0, stream>>>(idxw, cbb, wb7, h4t, stats);
  k8w<<<1, 256, 0, stream>>>(w2d, b2d, g4, bb4, stats, wbt, beta, (unsigned int*)h4t);
  k8<<<dim3(160,8), 256, 0, stream>>>(h4t, wbt, beta, h5b, stats);
  k9<<<dim3(40,8), 256, 0, stream>>>(h5b, w3d, b3d, g5, bb5, stats, out);
}

// Round 18
// 327.431 us; speedup vs baseline: 1.0169x; 1.0169x over previous
//
#include <hip/hip_runtime.h>
#include <hip/hip_bf16.h>

#define DEV __device__ __forceinline__

typedef __attribute__((ext_vector_type(8))) short s8v;     // 8 bf16 (4 VGPR)
typedef __attribute__((ext_vector_type(16))) float f32x16; // MFMA 32x32 acc
typedef __attribute__((address_space(1))) const unsigned int u32g;
typedef __attribute__((address_space(3))) unsigned int u32l;

DEV void gl_lds(const void* g, void* l){   // 16B async global->LDS
  __builtin_amdgcn_global_load_lds((u32g*)g, (u32l*)l, 16, 0, 0);
}

DEV float siluf(float x){ return x / (1.f + expf(-x)); }

DEV float wredsum(float v){
  #pragma unroll
  for(int m = 32; m; m >>= 1) v += __shfl_xor(v, m);
  return v;
}

DEV unsigned short bf16rne(float f){
  unsigned int u = __float_as_uint(f);
  u += 0x7FFFu + ((u >> 16) & 1u);
  return (unsigned short)(u >> 16);
}
DEV float bf16tof(unsigned short h){ return __uint_as_float(((unsigned int)h) << 16); }

// sk' = min(sk, max(bk, k)) given bk<=sk  ==  median(sk, bk, k), one VALU op.
DEV unsigned umed3(unsigned a, unsigned b, unsigned c){
  unsigned d;
  asm("v_med3_u32 %0, %1, %2, %3" : "=v"(d) : "v"(a), "v"(b), "v"(c));
  return d;
}

// ---- stats layout (float offsets within stats block) ----
#define S1 0
#define Q1 16
#define S2 32
#define Q2 64
#define S3 96
#define Q3 160
#define S4 224
#define Q4 288
#define S5 352
#define Q5 416
#define SLOSS 480
#define CNTOFF 500
#define NSTATF 512

#define EPSQ 6u
#define NCHUNK 8

// =========================================================================
// K_prep (merged): blocks [0,32): codebook -> cbsw/cnw/cnw2/cbb;
// blocks [32,632): enc_w3 -> w3t, dec_wt -> wb7.
__global__ void k_prep(const float* __restrict__ ew3, const float* __restrict__ dwt,
                       const float* __restrict__ cb, float* __restrict__ w3t,
                       unsigned short* __restrict__ wb7, unsigned short* __restrict__ cbsw,
                       float* __restrict__ cnw, float* __restrict__ cnw2,
                       unsigned short* __restrict__ cbb){
  int tid = threadIdx.x;
  if(blockIdx.x < 32){
    int j = blockIdx.x*256 + tid;
    float nrm = 0.f;
    unsigned swz = (j & 15) << 4;
    char* rowp = (char*)cbsw + (size_t)j*256;
    #pragma unroll
    for(int k = 0; k < 64; k++){
      float x = cb[(size_t)j*64 + k];
      unsigned short hi = bf16rne(x);
      float lo = x - bf16tof(hi);
      *(unsigned short*)(rowp + (((unsigned)(2*k)) ^ swz)) = hi;
      *(unsigned short*)(rowp + (((unsigned)(128 + 2*k)) ^ swz)) = bf16rne(lo);
      cbb[(size_t)j*64 + k] = hi;
      nrm = fmaf(x, x, nrm);
    }
    cnw[j] = nrm;
    cnw2[j] = (nrm + 1024.f) * 256.f;
    return;
  }
  const int n1 = 64*32*25, n2 = 64*64*25;
  for(int i = (blockIdx.x - 32)*256 + tid; i < n1+n2; i += 600*256){
    if(i < n1){
      int c = i/(32*25), r = i - c*(32*25), ii = r/25, k = r - ii*25;
      w3t[(ii*25 + k)*64 + c] = ew3[i];
    } else {
      int j = i - n1;
      int ii = j/(64*25), r = j - ii*(64*25), o = r/25, k = r - o*25;
      wb7[((size_t)(k*64 + o))*64 + ii] = bf16rne(dwt[j]);
    }
  }
}

// =========================================================================
// K1: conv1 (1->16, K=5, pad2) + silu + bn1 stats.
__global__ void k1(const float* __restrict__ x, const float* __restrict__ w1,
                   const float* __restrict__ b1, float* __restrict__ h1, float* stats){
  __shared__ float xs[136];
  __shared__ float ssum[16], ssq[16];
  int tid = threadIdx.x, b = blockIdx.y, t0 = blockIdx.x*128;
  if(tid < 16){ ssum[tid] = 0.f; ssq[tid] = 0.f; }
  for(int i = tid; i < 132; i += 256){
    int t = t0 + i - 2;
    xs[i] = (t >= 0 && t < 10240) ? x[b*10240 + t] : 0.f;
  }
  __syncthreads();
  int c = tid & 15, sgrp = tid >> 4;
  float w[5];
  #pragma unroll
  for(int k = 0; k < 5; k++) w[k] = w1[c*5 + k];
  float bias = b1[c];
  float outv[8];
  float ps = 0.f, pq = 0.f;
  #pragma unroll
  for(int s = 0; s < 8; s++){
    float a = bias;
    #pragma unroll
    for(int k = 0; k < 5; k++) a = fmaf(w[k], xs[sgrp*8 + s + k], a);
    a = siluf(a);
    outv[s] = a;
    ps += a; pq += a*a;
  }
  float* op = h1 + ((size_t)(b*16 + c))*10240 + t0 + sgrp*8;
  #pragma unroll
  for(int q = 0; q < 2; q++)
    *(float4*)(op + q*4) = make_float4(outv[q*4], outv[q*4+1], outv[q*4+2], outv[q*4+3]);
  ps += __shfl_xor(ps, 16); pq += __shfl_xor(pq, 16);
  ps += __shfl_xor(ps, 32); pq += __shfl_xor(pq, 32);
  if((tid & 48) == 0){ atomicAdd(&ssum[c], ps); atomicAdd(&ssq[c], pq); }
  __syncthreads();
  if(tid < 16){ atomicAdd(stats+S1+tid, ssum[tid]); atomicAdd(stats+Q1+tid, ssq[tid]); }
}

// =========================================================================
// K2: bn1 normalize + conv2 (16->32, K=5, pad2) + silu + bn2 stats.
__global__ __launch_bounds__(256) void k2(const float* __restrict__ h1,
                   const float* __restrict__ w2, const float* __restrict__ b2,
                   const float* __restrict__ g1, const float* __restrict__ bb1,
                   float* __restrict__ h2out, float* stats){
  __shared__ float hs[16][136];
  __shared__ float A1s[16], B1s[16];
  __shared__ float ssum[32], ssq[32];
  int tid = threadIdx.x, b = blockIdx.y, t0 = blockIdx.x*128;
  if(tid < 16){
    float mu = stats[S1+tid]/81920.f;
    float var = stats[Q1+tid]/81920.f - mu*mu;
    float rs = rsqrtf(var + 1e-5f);
    A1s[tid] = rs*g1[tid];
    B1s[tid] = bb1[tid] - mu*rs*g1[tid];
  }
  if(tid < 32){ ssum[tid] = 0.f; ssq[tid] = 0.f; }
  __syncthreads();
  {
    int ch = tid >> 4, j0 = tid & 15;
    float A = A1s[ch], B = B1s[ch];
    const float* hp = h1 + ((size_t)(b*16 + ch))*10240;
    for(int j = j0; j < 132; j += 16){
      int t = t0 + j - 2;
      hs[ch][j] = (t >= 0 && t < 10240) ? hp[t]*A + B : 0.f;
    }
  }
  __syncthreads();
  int c = tid & 31, tgrp = tid >> 5;
  int tb = tgrp*16;
  float acc[16];
  float bias = b2[c];
  #pragma unroll
  for(int s = 0; s < 16; s++) acc[s] = bias;
  for(int ic = 0; ic < 4; ic++){
    float wf[20];
    const float* wp = w2 + c*80 + ic*20;
    #pragma unroll
    for(int q = 0; q < 5; q++) *(float4*)(wf + q*4) = *(const float4*)(wp + q*4);
    #pragma unroll
    for(int di = 0; di < 4; di++){
      int i = ic*4 + di;
      float z[20];
      #pragma unroll
      for(int q = 0; q < 5; q++) *(float4*)(z + q*4) = *(const float4*)(&hs[i][tb] + q*4);
      float w0 = wf[di*5], w1 = wf[di*5+1], w2v = wf[di*5+2], w3 = wf[di*5+3], w4 = wf[di*5+4];
      #pragma unroll
      for(int s = 0; s < 16; s++)
        acc[s] = fmaf(w0, z[s], fmaf(w1, z[s+1], fmaf(w2v, z[s+2],
                 fmaf(w3, z[s+3], fmaf(w4, z[s+4], acc[s])))));
    }
  }
  float ps = 0.f, pq = 0.f;
  #pragma unroll
  for(int s = 0; s < 16; s++){
    float a = siluf(acc[s]);
    acc[s] = a;
    ps += a; pq += a*a;
  }
  float* op = h2out + ((size_t)(b*32 + c))*10240 + t0 + tb;
  #pragma unroll
  for(int q = 0; q < 4; q++)
    *(float4*)(op + q*4) = make_float4(acc[q*4], acc[q*4+1], acc[q*4+2], acc[q*4+3]);
  ps += __shfl_xor(ps, 32); pq += __shfl_xor(pq, 32);
  if((tid & 32) == 0){ atomicAdd(&ssum[c], ps); atomicAdd(&ssq[c], pq); }
  __syncthreads();
  if(tid < 32){ atomicAdd(stats+S2+tid, ssum[tid]); atomicAdd(stats+Q2+tid, ssq[tid]); }
}

// =========================================================================
// K3 (round-16 best-known): bn2 normalize + conv3 + tanh + bn3 stats.
__global__ void k3(const float* __restrict__ h2, const float* __restrict__ w3t,
                   const float* __restrict__ eb3, const float* __restrict__ g2,
                   const float* __restrict__ bb2, float* __restrict__ zn, float* stats){
  __shared__ __align__(16) float X[5*32*24];   // [kk][ch][m], m<20 valid
  __shared__ float A2[32], B2[32];
  __shared__ float ssum[64], ssq[64];
  int tid = threadIdx.x, b = blockIdx.y, l0 = blockIdx.x*16;
  if(tid < 32){
    float mu = stats[S2+tid]/81920.f;
    float var = stats[Q2+tid]/81920.f - mu*mu;
    float rs = rsqrtf(var + 1e-5f);
    A2[tid] = rs*g2[tid];
    B2[tid] = bb2[tid] - mu*rs*g2[tid];
  }
  if(tid < 64){ ssum[tid] = 0.f; ssq[tid] = 0.f; }
  __syncthreads();
  for(int i2 = tid; i2 < 5*32*20; i2 += 256){
    int kk = i2/640;
    int r  = i2 - kk*640;
    int ch = r/20, m = r - ch*20;
    int t = 5*(l0 + m) + kk - 12;
    float v = 0.f;
    if(t >= 0 && t < 10240) v = h2[((b*32+ch)*10240)+t]*A2[ch] + B2[ch];
    X[(kk*32+ch)*24 + m] = v;
  }
  __syncthreads();
  int c = tid & 63, lslot = tid >> 6;   // 4 slots x 4 l
  float acc[4];
  float bias = eb3[c];
  #pragma unroll
  for(int s = 0; s < 4; s++) acc[s] = bias;
  for(int i = 0; i < 32; i++){
    #pragma unroll
    for(int kk = 0; kk < 5; kk++){
      const float* xp = &X[(kk*32+i)*24 + lslot*4];
      float4 za = *(const float4*)(xp);
      float4 zb = *(const float4*)(xp + 4);
      float z[8] = {za.x,za.y,za.z,za.w,zb.x,zb.y,zb.z,zb.w};
      #pragma unroll
      for(int kap = 0; kap < 5; kap++){
        float w = w3t[(i*25 + kap*5 + kk)*64 + c];
        #pragma unroll
        for(int s = 0; s < 4; s++) acc[s] = fmaf(w, z[s+kap], acc[s]);
      }
    }
  }
  float ls = 0.f, lq = 0.f;
  #pragma unroll
  for(int s = 0; s < 4; s++){
    int l = l0 + lslot*4 + s;
    float a = tanhf(acc[s]);
    zn[((b*2048 + l)*64) + c] = a;
    ls += a; lq += a*a;
  }
  atomicAdd(&ssum[c], ls); atomicAdd(&ssq[c], lq);
  __syncthreads();
  if(tid < 64){ atomicAdd(stats+S3+tid, ssum[tid]); atomicAdd(stats+Q3+tid, ssq[tid]); }
}

// =========================================================================
// K5m: MFMA VQ pass (merged accumulator, (256,4)).
__global__ __launch_bounds__(256, 4) void k5m(const float* __restrict__ zn,
    const unsigned short* __restrict__ cbsw, const float* __restrict__ cnw2,
    const float* __restrict__ g3, const float* __restrict__ b3,
    const float* __restrict__ stats,
    unsigned int* __restrict__ pbk, unsigned int* __restrict__ psk){
  __shared__ __align__(16) unsigned char cbuf[2][16384];
  __shared__ float A3s[64], B3s[64];
  int tid = threadIdx.x;
  int chunk = blockIdx.x;
  int m0 = blockIdx.y * 128;
  int lane = tid & 63, wr = tid >> 6;
  int h = lane >> 5, cll = lane & 31;
  int row = m0 + wr*32 + cll;

  if(tid < 64){
    float mu = stats[S3+tid]/16384.f;
    float var = stats[Q3+tid]/16384.f - mu*mu;
    float rs = rsqrtf(var + 1e-5f);
    A3s[tid] = rs*g3[tid];
    B3s[tid] = b3[tid] - mu*rs*g3[tid];
  }

  int c0 = chunk * 1024;
  const char* csrc = (const char*)cbsw + (size_t)c0*256;
  #pragma unroll
  for(int c2 = 0; c2 < 4; c2++)
    gl_lds(csrc + c2*4096 + tid*16, &cbuf[0][0] + c2*4096 + tid*16);
  __syncthreads();

  s8v ah[4], al[4];
  const float* zp = zn + (size_t)row*64;
  #pragma unroll
  for(int s = 0; s < 4; s++){
    int koff = s*16 + h*8;
    float4 v0 = *(const float4*)(zp + koff);
    float4 v1 = *(const float4*)(zp + koff + 4);
    float vv[8] = {v0.x,v0.y,v0.z,v0.w,v1.x,v1.y,v1.z,v1.w};
    #pragma unroll
    for(int i = 0; i < 8; i++){
      float v = fmaf(vv[i], A3s[koff + i], B3s[koff + i]);
      unsigned short hi = bf16rne(v);
      ah[s][i] = (short)hi;
      al[s][i] = (short)bf16rne(v - bf16tof(hi));
    }
  }

  unsigned int bk[16], sk[16];
  #pragma unroll
  for(int r = 0; r < 16; r++){ bk[r] = 0xFFFFFFFFu; sk[r] = 0xFFFFFFFFu; }
  f32x16 zv;
  #pragma unroll
  for(int i = 0; i < 16; i++) zv[i] = 0.f;

  unsigned swz = (unsigned)(cll & 15) << 4;
  for(int tile = 0; tile < 16; ++tile){
    int bsel = tile & 1;
    if(tile < 15){
      const char* ns = csrc + (size_t)(tile+1)*16384;
      #pragma unroll
      for(int c2 = 0; c2 < 4; c2++)
        gl_lds(ns + c2*4096 + tid*16, &cbuf[bsel^1][0] + c2*4096 + tid*16);
    }
    #pragma unroll
    for(int half = 0; half < 2; half++){
      const unsigned char* bp = &cbuf[bsel][0] + (half*32 + cll)*256;
      s8v bh[4], bl[4];
      #pragma unroll
      for(int s = 0; s < 4; s++){
        bh[s] = *(const s8v*)(bp + (((unsigned)(s*32 + h*16)) ^ swz));
        bl[s] = *(const s8v*)(bp + (((unsigned)(128 + s*32 + h*16)) ^ swz));
      }
      unsigned col = (unsigned)(c0 + tile*64 + half*32 + cll);
      float cnv2 = cnw2[col];
      f32x16 a = __builtin_amdgcn_mfma_f32_32x32x16_bf16(ah[0], bl[0], zv, 0, 0, 0);
      a = __builtin_amdgcn_mfma_f32_32x32x16_bf16(al[0], bh[0], a, 0, 0, 0);
      a = __builtin_amdgcn_mfma_f32_32x32x16_bf16(ah[0], bh[0], a, 0, 0, 0);
      #pragma unroll
      for(int s = 1; s < 4; s++){
        a = __builtin_amdgcn_mfma_f32_32x32x16_bf16(ah[s], bl[s], a, 0, 0, 0);
        a = __builtin_amdgcn_mfma_f32_32x32x16_bf16(al[s], bh[s], a, 0, 0, 0);
        a = __builtin_amdgcn_mfma_f32_32x32x16_bf16(ah[s], bh[s], a, 0, 0, 0);
      }
      #pragma unroll
      for(int r = 0; r < 16; r++){
        float q = fmaf(-512.f, a[r], cnv2);
        q = fminf(q, 524287.f);
        unsigned k = (((unsigned)q) << 13) | col;
        unsigned nb = bk[r] < k ? bk[r] : k;
        sk[r] = umed3(sk[r], bk[r], k);
        bk[r] = nb;
      }
    }
    __syncthreads();
  }

  #pragma unroll
  for(int m = 1; m <= 16; m <<= 1){
    #pragma unroll
    for(int r = 0; r < 16; r++){
      unsigned int ob = (unsigned int)__shfl_xor((int)bk[r], m);
      unsigned int os = (unsigned int)__shfl_xor((int)sk[r], m);
      unsigned int s2 = sk[r] < os ? sk[r] : os;
      sk[r] = umed3(s2, bk[r], ob);
      bk[r] = bk[r] < ob ? bk[r] : ob;
    }
  }
  if(cll == 0){
    size_t base = (size_t)chunk*16384 + m0 + wr*32 + 4*h;
    #pragma unroll
    for(int r = 0; r < 16; r++){
      int lr = (r&3) + 8*(r>>2);
      pbk[base + lr] = bk[r];
      psk[base + lr] = sk[r];
    }
  }
}

// =========================================================================
// K5r: merge chunk partials; write idx; flag close calls; loss for unflagged.
__global__ void k5r(const unsigned int* __restrict__ pbk,
                    const unsigned int* __restrict__ psk,
                    const float* __restrict__ zn, const float* __restrict__ cb,
                    const float* __restrict__ g3, const float* __restrict__ b3,
                    int* __restrict__ idxw, float* __restrict__ out_idx,
                    int* __restrict__ list, int* cnt, float* stats){
  __shared__ float A3s[64], B3s[64];
  int tid = threadIdx.x;
  if(tid < 64){
    float mu = stats[S3+tid]/16384.f;
    float var = stats[Q3+tid]/16384.f - mu*mu;
    float rs = rsqrtf(var + 1e-5f);
    A3s[tid] = rs*g3[tid];
    B3s[tid] = b3[tid] - mu*rs*g3[tid];
  }
  __syncthreads();
  int row = blockIdx.x*256 + tid;  // grid 64
  unsigned int bk = pbk[row], sk = psk[row];
  #pragma unroll
  for(int c = 1; c < NCHUNK; c++){
    unsigned int ob = pbk[(size_t)c*16384 + row];
    unsigned int os = psk[(size_t)c*16384 + row];
    unsigned int s2 = sk < os ? sk : os;
    sk = umed3(s2, bk, ob);
    bk = bk < ob ? bk : ob;
  }
  int idx = (int)(bk & 0x1FFFu);
  idxw[row] = idx;
  out_idx[row] = (float)idx;
  bool flag = ((sk >> 13) - (bk >> 13)) <= EPSQ;
  if(flag){
    int p = atomicAdd(cnt, 1);
    list[p] = row;
  }
  float s = 0.f;
  if(!flag){
    const float* cp = cb + (size_t)idx*64;
    const float* zp = zn + (size_t)row*64;
    #pragma unroll
    for(int k = 0; k < 64; k++){
      float v = fmaf(zp[k], A3s[k], B3s[k]);
      float dd = cp[k] - v;
      s = fmaf(dd, dd, s);
    }
  }
  float tot = wredsum(s);
  if((tid & 63) == 0) atomicAdd(stats + SLOSS, tot);
}

// =========================================================================
// K5x: exact f32 rescore, row-parallel; bn3 affine applied on z-row load.
__global__ __launch_bounds__(256) void k5x(const float* __restrict__ zn,
    const float* __restrict__ cb, const float* __restrict__ cnw,
    const float* __restrict__ g3, const float* __restrict__ b3,
    const float* __restrict__ stats,
    const int* __restrict__ list, const int* cnt,
    float* __restrict__ pxd, int* __restrict__ pxi){
  __shared__ float A3s[64], B3s[64];
  int tid = threadIdx.x;
  if(tid < 64){
    float mu = stats[S3+tid]/16384.f;
    float var = stats[Q3+tid]/16384.f - mu*mu;
    float rs = rsqrtf(var + 1e-5f);
    A3s[tid] = rs*g3[tid];
    B3s[tid] = b3[tid] - mu*rs*g3[tid];
  }
  __syncthreads();
  int chunk = blockIdx.x;
  int n = *cnt;
  int rgrp = tid >> 6, cs = tid & 63;
  int c0 = chunk * 1024;
  for(int bat = blockIdx.y; bat*4 < n; bat += 256){
    int e = bat*4 + rgrp;
    int ec = e < n ? e : n-1;
    int row = list[ec];
    float4 zr[16];
    const float4* zp = (const float4*)(zn + (size_t)row*64);
    #pragma unroll
    for(int q = 0; q < 16; q++){
      float4 v = zp[q];
      v.x = fmaf(v.x, A3s[q*4+0], B3s[q*4+0]);
      v.y = fmaf(v.y, A3s[q*4+1], B3s[q*4+1]);
      v.z = fmaf(v.z, A3s[q*4+2], B3s[q*4+2]);
      v.w = fmaf(v.w, A3s[q*4+3], B3s[q*4+3]);
      zr[q] = v;
    }
    float bd = 3.4e38f; int bi = 0;
    for(int step = 0; step < 16; step++){
      int j = c0 + step*64 + cs;
      const float4* cp = (const float4*)(cb + (size_t)j*64);
      float cnv = cnw[j];
      float da = 0.f, db = 0.f;
      #pragma unroll
      for(int q = 0; q < 16; q += 2){
        float4 ca = cp[q], cb4 = cp[q+1];
        da = fmaf(ca.x, zr[q].x, da);  da = fmaf(ca.y, zr[q].y, da);
        da = fmaf(ca.z, zr[q].z, da);  da = fmaf(ca.w, zr[q].w, da);
        db = fmaf(cb4.x, zr[q+1].x, db); db = fmaf(cb4.y, zr[q+1].y, db);
        db = fmaf(cb4.z, zr[q+1].z, db); db = fmaf(cb4.w, zr[q+1].w, db);
      }
      float d = fmaf(-2.f, da + db, cnv);
      if(d < bd){ bd = d; bi = j; }
    }
    #pragma unroll
    for(int m = 1; m <= 32; m <<= 1){
      float od = __shfl_xor(bd, m);
      int   oi = __shfl_xor(bi, m);
      if(od < bd || (od == bd && oi < bi)){ bd = od; bi = oi; }
    }
    if(cs == 0 && e < n){
      pxd[(size_t)chunk*16384 + e] = bd;
      pxi[(size_t)chunk*16384 + e] = bi;
    }
  }
}

// =========================================================================
// K5x2: merge chunk partials per flagged row -> final idx; add flagged loss.
__global__ void k5x2(const float* __restrict__ pxd, const int* __restrict__ pxi,
                     const float* __restrict__ zn, const float* __restrict__ cb,
                     const float* __restrict__ g3, const float* __restrict__ b3,
                     const int* __restrict__ list, const int* cnt,
                     int* __restrict__ idxw, float* __restrict__ out_idx,
                     float* stats){
  __shared__ float A3s[64], B3s[64];
  int tid = threadIdx.x;
  if(tid < 64){
    float mu = stats[S3+tid]/16384.f;
    float var = stats[Q3+tid]/16384.f - mu*mu;
    float rs = rsqrtf(var + 1e-5f);
    A3s[tid] = rs*g3[tid];
    B3s[tid] = b3[tid] - mu*rs*g3[tid];
  }
  __syncthreads();
  int e = blockIdx.x*256 + tid;  // grid 64
  int n = *cnt;
  if(e < n){
    float bd = pxd[e]; int bi = pxi[e];
    #pragma unroll
    for(int c = 1; c < NCHUNK; c++){
      float od = pxd[(size_t)c*16384 + e];
      int   oi = pxi[(size_t)c*16384 + e];
      if(od < bd || (od == bd && oi < bi)){ bd = od; bi = oi; }
    }
    int row = list[e];
    idxw[row] = bi;
    out_idx[row] = (float)bi;
    float s = 0.f;
    const float* cp = cb + (size_t)bi*64;
    const float* zp = zn + (size_t)row*64;
    #pragma unroll
    for(int k = 0; k < 64; k++){
      float v = fmaf(zp[k], A3s[k], B3s[k]);
      float dd = cp[k] - v;
      s = fmaf(dd, dd, s);
    }
    atomicAdd(stats + SLOSS, s);
  }
}

// =========================================================================
// K7m: transposed conv as MFMA GEMM.
__global__ __launch_bounds__(320) void k7m(const int* __restrict__ idxp,
    const unsigned short* __restrict__ cbb, const unsigned short* __restrict__ wb7,
    unsigned short* __restrict__ h4t, float* stats){
  __shared__ __align__(16) unsigned char lA[37*128];
  __shared__ float tb[5*64*33];
  __shared__ float ssum[64], ssq[64];
  int tid = threadIdx.x, b = blockIdx.y, u0 = blockIdx.x*32;
  if(tid < 64){ ssum[tid] = 0.f; ssq[tid] = 0.f; }
  {
    int m = tid >> 3, part = tid & 7;
    if(m < 37){
      int u = u0 - 2 + m;
      uint4 val = make_uint4(0,0,0,0);
      if(u >= 0 && u < 2048){
        int code = idxp[b*2048 + u];
        val = *(const uint4*)((const char*)cbb + (size_t)code*128 + part*16);
      }
      *(uint4*)(lA + m*128 + (((unsigned)(part*16)) ^ (((unsigned)m & 7) << 4))) = val;
    }
  }
  __syncthreads();
  int lane = tid & 63, h = lane >> 5, cl = lane & 31;
  int v = tid >> 6;
  const int km[5]  = {2,3,4,0,1};
  const int ovv[5] = {2,2,2,3,3};
  f32x16 acc0, acc1;
  #pragma unroll
  for(int i = 0; i < 16; i++){ acc0[i] = 0.f; acc1[i] = 0.f; }
  #pragma unroll
  for(int r = 0; r < 5; r++){
    int off = ovv[v] - r + 2;
    int m = cl + off;
    unsigned aswz = ((unsigned)m & 7) << 4;
    int k = km[v] + 5*r;
    const char* b0p = (const char*)wb7 + (size_t)(k*64 + cl)*128;
    const char* b1p = b0p + 32*128;
    #pragma unroll
    for(int s = 0; s < 4; s++){
      unsigned o = (unsigned)(s*32 + h*16);
      s8v a  = *(const s8v*)(lA + m*128 + (o ^ aswz));
      s8v b0 = *(const s8v*)(b0p + o);
      s8v b1 = *(const s8v*)(b1p + o);
      acc0 = __builtin_amdgcn_mfma_f32_32x32x16_bf16(a, b0, acc0, 0, 0, 0);
      acc1 = __builtin_amdgcn_mfma_f32_32x32x16_bf16(a, b1, acc1, 0, 0, 0);
    }
  }
  float ps0 = 0.f, pq0 = 0.f, ps1 = 0.f, pq1 = 0.f;
  #pragma unroll
  for(int r = 0; r < 16; r++){
    int ul = (r&3) + 8*(r>>2) + 4*h;
    int u = u0 + ul;
    float v0 = siluf(acc0[r]), v1 = siluf(acc1[r]);
    tb[(v*64 + cl)*33 + ul]      = v0;
    tb[(v*64 + 32 + cl)*33 + ul] = v1;
    if(v == 0 || u < 2047){ ps0 += v0; pq0 += v0*v0; ps1 += v1; pq1 += v1*v1; }
  }
  atomicAdd(&ssum[cl], ps0);      atomicAdd(&ssq[cl], pq0);
  atomicAdd(&ssum[32 + cl], ps1); atomicAdd(&ssq[32 + cl], pq1);
  __syncthreads();
  if(tid < 64){ atomicAdd(stats+S4+tid, ssum[tid]); atomicAdd(stats+Q4+tid, ssq[tid]); }
  #pragma unroll
  for(int j = 0; j < 16; j++){
    int flat = j*320 + tid;
    int tl = flat >> 5;
    int chp = flat & 31;
    int t = u0*5 + tl;
    if(t < 10236){
      int vv = tl % 5, ul = tl / 5;
      float f0 = tb[(vv*64 + 2*chp)*33 + ul];
      float f1 = tb[(vv*64 + 2*chp + 1)*33 + ul];
      unsigned int pk = (unsigned int)bf16rne(f0) | ((unsigned int)bf16rne(f1) << 16);
      size_t rowb = ((size_t)b*10248 + 2 + t)*128;
      *(unsigned int*)((char*)h4t + rowb + (((unsigned)(4*chp)) ^ (((unsigned)t & 7) << 4))) = pk;
    }
  }
}

// =========================================================================
// K8w: fold dbn1 into decoder conv2 weights + beta; also zero h4t pad rows.
__global__ void k8w(const float* __restrict__ w2d, const float* __restrict__ b2d,
                    const float* __restrict__ g4, const float* __restrict__ bb4,
                    const float* __restrict__ stats, unsigned short* __restrict__ wbt,
                    float* __restrict__ beta, unsigned int* __restrict__ h4tz){
  __shared__ float A4[64], B4[64];
  int tid = threadIdx.x;
  for(int i = tid; i < 3072; i += 256){
    int b = i / 384, r = i - b*384;
    int row12 = r >> 5, word = r & 31;
    int row = row12 < 2 ? row12 : 10236 + row12;
    h4tz[((size_t)b*10248 + row)*32 + word] = 0u;
  }
  if(tid < 64){
    float mu = stats[S4+tid]/81888.f;
    float var = stats[Q4+tid]/81888.f - mu*mu;
    float rs = rsqrtf(var + 1e-5f);
    A4[tid] = rs*g4[tid];
    B4[tid] = bb4[tid] - mu*rs*g4[tid];
  }
  __syncthreads();
  for(int e = tid; e < 64*64*5; e += 256){
    int c = e/320, r = e - c*320, i = r/5, k = r - i*5;
    unsigned short hw = bf16rne(w2d[e] * A4[i]);
    int row = k*64 + c;
    *(unsigned short*)((char*)wbt + (size_t)row*128 + (((unsigned)(2*i)) ^ (((unsigned)c & 7) << 4))) = hw;
  }
  if(tid < 64){
    float s = b2d[tid];
    for(int i = 0; i < 64; i++){
      float wsum = 0.f;
      #pragma unroll
      for(int k = 0; k < 5; k++) wsum += w2d[(tid*64 + i)*5 + k];
      s += wsum * B4[i];
    }
    beta[tid] = s;
  }
}

// =========================================================================
// K8: decoder conv2 as MFMA GEMM.
__global__ __launch_bounds__(256) void k8(const unsigned short* __restrict__ h4t,
    const unsigned short* __restrict__ wbt, const float* __restrict__ beta,
    unsigned short* __restrict__ h5b, float* stats){
  __shared__ __align__(16) unsigned char lA[68*128];
  __shared__ float ssum[64], ssq[64];
  int tid = threadIdx.x, b = blockIdx.y, t0 = blockIdx.x*64;
  if(tid < 64){ ssum[tid] = 0.f; ssq[tid] = 0.f; }
  const char* srcA = (const char*)h4t + ((size_t)b*10248 + t0)*128;
  #pragma unroll
  for(int c2 = 0; c2 < 2; c2++)
    gl_lds(srcA + c2*4096 + tid*16, lA + c2*4096 + tid*16);
  if(tid < 32) gl_lds(srcA + 8192 + tid*16, lA + 8192 + tid*16);
  __syncthreads();

  int lane = tid & 63, h = lane >> 5, cl = lane & 31;
  int widx = tid >> 6;
  int wt0 = (widx >> 1) * 32;
  int wch = (widx & 1) * 32;
  f32x16 acc;
  #pragma unroll
  for(int i = 0; i < 16; i++) acc[i] = 0.f;
  unsigned bswz = (unsigned)(cl & 7) << 4;
  #pragma unroll
  for(int k = 0; k < 5; k++){
    int l = wt0 + cl + k;
    unsigned aswz = (unsigned)((l + 6) & 7) << 4;
    const char* bp = (const char*)wbt + (size_t)(k*64 + wch + cl)*128;
    #pragma unroll
    for(int s = 0; s < 4; s++){
      unsigned o = (unsigned)(s*32 + h*16);
      s8v a  = *(const s8v*)(lA + l*128 + (o ^ aswz));
      s8v bb = *(const s8v*)(bp + (o ^ bswz));
      acc = __builtin_amdgcn_mfma_f32_32x32x16_bf16(a, bb, acc, 0, 0, 0);
    }
  }
  float bet = beta[wch + cl];
  float ps = 0.f, pq = 0.f;
  #pragma unroll
  for(int r = 0; r < 16; r++){
    int t = t0 + wt0 + (r&3) + 8*(r>>2) + 4*h;
    float v0 = siluf(acc[r] + bet);
    if(t < 10236){
      h5b[((size_t)b*10240 + t)*64 + wch + cl] = bf16rne(v0);
      ps += v0; pq += v0*v0;
    }
  }
  atomicAdd(&ssum[wch + cl], ps); atomicAdd(&ssq[wch + cl], pq);
  __syncthreads();
  if(tid < 64){ atomicAdd(stats+S5+tid, ssum[tid]); atomicAdd(stats+Q5+tid, ssq[tid]); }
}

// =========================================================================
// K9: dbn2 normalize + 1x1 conv (64->1) + bias; also writes commit loss.
__global__ void k9(const unsigned short* __restrict__ h5b, const float* __restrict__ w3,
                   const float* __restrict__ b3, const float* __restrict__ g5,
                   const float* __restrict__ bb5, const float* stats,
                   float* __restrict__ out){
  __shared__ float WA[64], WB[64];
  int tid = threadIdx.x;
  if(blockIdx.x == 0 && blockIdx.y == 0 && tid == 0)
    out[98304] = 2.f * stats[SLOSS] / 1048576.f;
  if(tid < 64){
    float mu = stats[S5+tid]/81888.f;
    float var = stats[Q5+tid]/81888.f - mu*mu;
    float rs = rsqrtf(var + 1e-5f);
    float A = rs*g5[tid], B = bb5[tid] - mu*rs*g5[tid];
    float w = w3[tid];
    WA[tid] = w*A; WB[tid] = w*B;
  }
  __syncthreads();
  int b = blockIdx.y;
  int t = blockIdx.x*256 + tid;
  float acc = b3[0];
  if(t < 10236){
    const unsigned short* hp = h5b + ((size_t)b*10240 + t)*64;
    #pragma unroll
    for(int q = 0; q < 8; q++){
      uint4 u = *(const uint4*)(hp + q*8);
      unsigned int ua[4] = {u.x, u.y, u.z, u.w};
      #pragma unroll
      for(int w = 0; w < 4; w++){
        int c = q*8 + w*2;
        acc += WA[c]*bf16tof((unsigned short)(ua[w] & 0xFFFFu)) + WB[c];
        acc += WA[c+1]*bf16tof((unsigned short)(ua[w] >> 16)) + WB[c+1];
      }
    }
  } else acc = 0.f;
  out[b*10240 + t] = acc;
}

// =========================================================================
extern "C" void kernel_launch(void* const* d_in, const int* in_sizes, int n_in,
                              void* d_out, int out_size, void* d_ws, size_t ws_size,
                              hipStream_t stream){
  const float* x   = (const float*)d_in[0];
  const float* ew1 = (const float*)d_in[1];
  const float* eb1 = (const float*)d_in[2];
  const float* g1  = (const float*)d_in[3];
  const float* bb1 = (const float*)d_in[4];
  const float* ew2 = (const float*)d_in[5];
  const float* eb2 = (const float*)d_in[6];
  const float* g2  = (const float*)d_in[7];
  const float* bb2 = (const float*)d_in[8];
  const float* ew3 = (const float*)d_in[9];
  const float* eb3 = (const float*)d_in[10];
  const float* g3  = (const float*)d_in[11];
  const float* bb3 = (const float*)d_in[12];
  const float* cb  = (const float*)d_in[13];
  const float* dwt = (const float*)d_in[14];
  const float* g4  = (const float*)d_in[15];
  const float* bb4 = (const float*)d_in[16];
  const float* w2d = (const float*)d_in[17];
  const float* b2d = (const float*)d_in[18];
  const float* g5  = (const float*)d_in[19];
  const float* bb5 = (const float*)d_in[20];
  const float* w3d = (const float*)d_in[21];
  const float* b3d = (const float*)d_in[22];

  char* ws = (char*)d_ws;
  float* h1   = (float*)(ws + 0);                           // k1->k2
  unsigned short* h4t = (unsigned short*)(ws + 0);          // 10,493,952 (k7m+)
  float* h2   = (float*)(ws + 5242880);
  float* zn   = (float*)(ws + 15728640);
  unsigned short* h5b = (unsigned short*)(ws + 20971520);   // 10,485,760 (k8+)
  int*   list = (int*)  (ws + 20971520);                    // 65,536 (k5r..k5x2, pre-k7m)
  unsigned int* pbk = (unsigned int*)(ws + 21037312);       // 524,288 (k5m+)
  unsigned int* psk = (unsigned int*)(ws + 21561600);       // 524,288
  float* pxd  = (float*)(ws + 22085888);                    // 524,288 (k5x+)
  int*   pxi  = (int*)  (ws + 22610176);                    // 524,288
  unsigned short* wbt = (unsigned short*)(ws + 31457280);   // 40,960 (k8w+)
  float* beta = (float*)(ws + 31498240);                    // 256
  unsigned short* wb7 = (unsigned short*)(ws + 32000000);   // 204,800
  unsigned short* cbb = (unsigned short*)(ws + 32300032);   // 1,048,576
  float* w3t  = (float*)(ws + 33400000);                    // 204,800
  unsigned short* cbsw = (unsigned short*)(ws + 34000000);  // 2,097,152
  float* cnw  = (float*)(ws + 36100096);                    // 32,768
  float* cnw2 = (float*)(ws + 36150016);                    // 32,768
  int*   idxw = (int*)  (ws + 42549248);
  float* stats= (float*)(ws + 42614784);
  int*   cnt  = (int*)(stats + CNTOFF);                     // inside memset-zeroed stats
  if(ws_size < 42616832) return;

  float* out = (float*)d_out;  // f32: [recon 81920][idx 16384][loss 1]

  hipMemsetAsync(stats, 0, NSTATF*4, stream);
  k_prep<<<632, 256, 0, stream>>>(ew3, dwt, cb, w3t, wb7, cbsw, cnw, cnw2, cbb);
  k1<<<dim3(80,8), 256, 0, stream>>>(x, ew1, eb1, h1, stats);
  k2<<<dim3(80,8), 256, 0, stream>>>(h1, ew2, eb2, g1, bb1, h2, stats);
  k3<<<dim3(128,8), 256, 0, stream>>>(h2, w3t, eb3, g2, bb2, zn, stats);
  k5m<<<dim3(NCHUNK,128), 256, 0, stream>>>(zn, cbsw, cnw2, g3, bb3, stats, pbk, psk);
  k5r<<<64, 256, 0, stream>>>(pbk, psk, zn, cb, g3, bb3, idxw, out + 81920, list, cnt, stats);
  k5x<<<dim3(NCHUNK,256), 256, 0, stream>>>(zn, cb, cnw, g3, bb3, stats, list, cnt, pxd, pxi);
  k5x2<<<64, 256, 0, stream>>>(pxd, pxi, zn, cb, g3, bb3, list, cnt, idxw, out + 81920, stats);
  k7m<<<dim3(64,8), 320, 0, stream>>>(idxw, cbb, wb7, h4t, stats);
  k8w<<<1, 256, 0, stream>>>(w2d, b2d, g4, bb4, stats, wbt, beta, (unsigned int*)h4t);
  k8<<<dim3(160,8), 256, 0, stream>>>(h4t, wbt, beta, h5b, stats);
  k9<<<dim3(40,8), 256, 0, stream>>>(h5b, w3d, b3d, g5, bb5, stats, out);
}